// Round 8
// baseline (253.544 us; speedup 1.0000x reference)
//
#include <hip/hip_runtime.h>

// ---------------------------------------------------------------------------
// ImageTextModule: dual cross-attention between text and image feature sets.
//   t = text @ w_text^T + b_text ; i = image @ w_image^T + b_image  (bf16)
//   P  = exp((t @ i^T) / 32)  materialized ONCE in bf16, BOTH layouts (P, PT);
//        row/col exp-sums fused (1 atomic per row/col per block).
//   out0 = (scale_TI / lT) * P  @ image ; out1 = (scale_IT / lI) * PT @ text
// attn (v3, r2-verified): fine-phase counted-vmcnt pipeline. 256x128 tile,
//   512 thr / 8 waves; 3-slot LDS ring (144 KB dynamic); vmcnt(6)+lgkmcnt(0)
//   gate per tile; chunk16^=(row&7) swizzle both-sides -> conflicts 0.
//   68.2 µs = fabric floor (768 MB reads / ~11.5 TB/s). AT ROOFLINE for this
//   decomposition. FAILED attacks (do not retry): A-from-global regs (r4:
//   158 µs); XCD remap (r5: 73.8 µs, FETCH 98->139 MB, L3-fit broken).
// logits (v4, THIS round): ledger re-derivation: ~14 attn dispatches at
//   68.0-68.9 fill the top-5, so logits ≈ 68 µs hides at the cutoff — the
//   co-largest kernel, fabric-bound (512 MB reads at only 7.5 TB/s: serial
//   epilogue doesn't overlap). Fix: 256x128 tile (reads 512->384 MB, -25%)
//   at 512 thr / 8 waves (attn3 wave math, acc[4][4]) while KEEPING ~3
//   blk/CU (50.5 KB LDS: 48 KB K-buf + 2.5 KB reduction scratch; r3's
//   failure was 1 blk/CU, not tile size). Epilogue: P/PT staged in 128-row
//   (col) halves at stride 140 (conflict-free), K-buf region reused; 8-wave
//   lred[256]/cred[3][128] reduction = the r3-refcheck'd logic.
//   K-loop swizzle r7: NULL (2-phase regime hides LDS conflicts — T2 gate).
// proj (v3, r6): attn3 pipeline at LD=1024, 16 K-tiles, bias epilogue.
// Workspace: 96 MB + 32 KB.
// ---------------------------------------------------------------------------

typedef __bf16 bf16x8 __attribute__((ext_vector_type(8)));
typedef float f32x4 __attribute__((ext_vector_type(4)));

#define N_T 4096
#define N_I 4096
#define DIM 1024
#define PSS 140  // logits epilogue half-tile stride (bf16): 128 + 12

// ring slot: A 256x64 bf16 (16384 sh) + B 128x64 bf16 (8192 sh) = 48 KB
#define AT_SLOT 24576
#define AT_LDS_BYTES (3 * AT_SLOT * 2)  // 147456 B = 144 KB
// logits: K-buf 48 KB (also reused as 128x140 staging) + 640 f32 scratch
#define LG_LDS_BYTES (AT_SLOT * 2 + 640 * 4)  // 51712 B

__device__ __forceinline__ unsigned short f2bf(float f) {
    unsigned int u = __float_as_uint(f);
    u += 0x7fffu + ((u >> 16) & 1u);  // RNE
    return (unsigned short)(u >> 16);
}

// 16-byte async global->LDS DMA (no VGPR round-trip).
__device__ __forceinline__ void async_cp16(const unsigned short* g, unsigned short* l) {
    __builtin_amdgcn_global_load_lds(
        (const __attribute__((address_space(1))) unsigned int*)g,
        (__attribute__((address_space(3))) unsigned int*)l, 16, 0, 0);
}

// Coalesced 128x128 bf16 tile store from LDS (stride PSS), 512 threads.
__device__ __forceinline__ void tile_store512(const unsigned short* smp,
                                              unsigned short* __restrict__ g, int ld,
                                              int row0, int col0, int tid) {
    int r = tid >> 2, h = (tid & 3) << 5;  // 4 thr/row, 64 B each
    const unsigned short* src = smp + r * PSS + h;
    unsigned short* dst = g + (size_t)(row0 + r) * ld + col0 + h;
#pragma unroll
    for (int v = 0; v < 4; ++v)
        *(uint4*)(dst + v * 8) = *(const uint4*)(src + v * 8);
}

// ---- fine-phase pipeline stagers (attn + proj + logits) --------------------
// LDS tile [R][64] bf16: 16B-chunk index within a row ^= (row & 7) ->
// conflict-free ds_read_b128 (verified 0). Applied BOTH at the gload source
// (inverse) and the ds_read address (rule 21).

// Stage A half h (128 rows, 1024 chunks, 2 per thread of 512; dest linear).
template <int LD>
__device__ __forceinline__ void at_stageA_half(const unsigned short* __restrict__ g,
                                               int row0, int k0, unsigned short* lds,
                                               int t, int h) {
#pragma unroll
    for (int u = 0; u < 2; ++u) {
        int c = t + (h * 2 + u) * 512;
        int r = c >> 3;
        int kq = (c & 7) ^ (r & 7);  // inverse-swizzled global chunk
        async_cp16(g + (size_t)(row0 + r) * LD + k0 + (kq << 3), lds + c * 8);
    }
}

// Stage B half h (64 rows, 512 chunks, 1 per thread).
template <int LD>
__device__ __forceinline__ void at_stageB_half(const unsigned short* __restrict__ g,
                                               int row0, int k0, unsigned short* lds,
                                               int t, int h) {
    int c = t + h * 512;
    int r = c >> 3;
    int kq = (c & 7) ^ (r & 7);
    async_cp16(g + (size_t)(row0 + r) * LD + k0 + (kq << 3), lds + c * 8);
}

// Full-tile stagers.
template <int LD>
__device__ __forceinline__ void at_stageA(const unsigned short* __restrict__ g,
                                          int row0, int k0, unsigned short* lds, int t) {
    at_stageA_half<LD>(g, row0, k0, lds, t, 0);
    at_stageA_half<LD>(g, row0, k0, lds, t, 1);
}
template <int LD>
__device__ __forceinline__ void at_stageB(const unsigned short* __restrict__ g,
                                          int row0, int k0, unsigned short* lds, int t) {
    at_stageB_half<LD>(g, row0, k0, lds, t, 0);
    at_stageB_half<LD>(g, row0, k0, lds, t, 1);
}

// One sub-phase: 8 swizzled ds_read_b128 (K-slice ks of slot cp) + optional
// stage-half ks of a later tile into nsl + 16 MFMA under setprio(1).
template <int LD, int DO_STAGE>
__device__ __forceinline__ void at_sub(const unsigned short* cp,
                                       const unsigned short* __restrict__ A,
                                       const unsigned short* __restrict__ Bt,
                                       int m0, int n0, int kst, unsigned short* nsl,
                                       int t, f32x4 acc[4][4],
                                       int wrow, int wcol, int lane16, int quad, int ks) {
    const unsigned short* As = cp;
    const unsigned short* Bs = cp + 16384;
    bf16x8 a[4], b[4];
    int sw = (((ks << 2) | quad) ^ (lane16 & 7)) << 3;  // row&7 == lane16&7
#pragma unroll
    for (int i = 0; i < 4; ++i)
        a[i] = *(const bf16x8*)&As[(wrow + i * 16 + lane16) * 64 + sw];
#pragma unroll
    for (int j = 0; j < 4; ++j)
        b[j] = *(const bf16x8*)&Bs[(wcol + j * 16 + lane16) * 64 + sw];
    if (DO_STAGE) {
        at_stageA_half<LD>(A, m0, kst, nsl, t, ks);
        at_stageB_half<LD>(Bt, n0, kst, nsl + 16384, t, ks);
    }
    __builtin_amdgcn_s_setprio(1);
#pragma unroll
    for (int i = 0; i < 4; ++i)
#pragma unroll
        for (int j = 0; j < 4; ++j)
            acc[i][j] = __builtin_amdgcn_mfma_f32_16x16x32_bf16(a[i], b[j], acc[i][j], 0, 0, 0);
    __builtin_amdgcn_s_setprio(0);
}

// ---- unified pre-pass ------------------------------------------------------
// z=0: image 64x64 tile -> image_bf + imgT      z=1: text -> text_bf + textT
// z=2: weights flat cvt (lin id over 1024 blocks); blocks 0-3 zero lT/lI.
__global__ void __launch_bounds__(256)
cvt_all(const float* __restrict__ im, const float* __restrict__ tx,
        const float* __restrict__ wt, const float* __restrict__ wi,
        unsigned short* __restrict__ imb, unsigned short* __restrict__ txb,
        unsigned short* __restrict__ imgT, unsigned short* __restrict__ textT,
        unsigned short* __restrict__ wtb, unsigned short* __restrict__ wib,
        float* __restrict__ lTI) {
    int t = threadIdx.x;
    if (blockIdx.z == 2) {
        int lin = blockIdx.y * 64 + blockIdx.x;  // 0..1023
        if (lin < 4) {
            *(f32x4*)&lTI[(lin * 256 + t) * 8] = (f32x4){0.f, 0.f, 0.f, 0.f};
            *(f32x4*)&lTI[(lin * 256 + t) * 8 + 4] = (f32x4){0.f, 0.f, 0.f, 0.f};
        }
        size_t i = (size_t)(lin * 256 + t) * 8;
        const float* s;
        unsigned short* d;
        size_t off;
        if (i < 1048576) { s = wt; d = wtb; off = i; }
        else             { s = wi; d = wib; off = i - 1048576; }
        float4 f0 = *(const float4*)(s + off);
        float4 f1 = *(const float4*)(s + off + 4);
        uint4 o;
        o.x = (unsigned int)f2bf(f0.x) | ((unsigned int)f2bf(f0.y) << 16);
        o.y = (unsigned int)f2bf(f0.z) | ((unsigned int)f2bf(f0.w) << 16);
        o.z = (unsigned int)f2bf(f1.x) | ((unsigned int)f2bf(f1.y) << 16);
        o.w = (unsigned int)f2bf(f1.z) | ((unsigned int)f2bf(f1.w) << 16);
        *(uint4*)(d + off) = o;
        return;
    }
    const float* in = blockIdx.z ? tx : im;
    unsigned short* nb = blockIdx.z ? txb : imb;
    unsigned short* tr = blockIdx.z ? textT : imgT;
    __shared__ float tile[64][65];
    int row0 = blockIdx.x * 64, col0 = blockIdx.y * 64;
    int r = t >> 2, c = (t & 3) << 4;  // 64 rows x 4 col-chunks of 16
    {
        const float* p = in + (size_t)(row0 + r) * DIM + col0 + c;
        float4 f0 = *(const float4*)(p);
        float4 f1 = *(const float4*)(p + 4);
        float4 f2 = *(const float4*)(p + 8);
        float4 f3 = *(const float4*)(p + 12);
        *(float4*)&tile[r][c] = f0;
        *(float4*)&tile[r][c + 4] = f1;
        *(float4*)&tile[r][c + 8] = f2;
        *(float4*)&tile[r][c + 12] = f3;
        uint4 o0, o1;
        o0.x = (unsigned int)f2bf(f0.x) | ((unsigned int)f2bf(f0.y) << 16);
        o0.y = (unsigned int)f2bf(f0.z) | ((unsigned int)f2bf(f0.w) << 16);
        o0.z = (unsigned int)f2bf(f1.x) | ((unsigned int)f2bf(f1.y) << 16);
        o0.w = (unsigned int)f2bf(f1.z) | ((unsigned int)f2bf(f1.w) << 16);
        o1.x = (unsigned int)f2bf(f2.x) | ((unsigned int)f2bf(f2.y) << 16);
        o1.y = (unsigned int)f2bf(f2.z) | ((unsigned int)f2bf(f2.w) << 16);
        o1.z = (unsigned int)f2bf(f3.x) | ((unsigned int)f2bf(f3.y) << 16);
        o1.w = (unsigned int)f2bf(f3.z) | ((unsigned int)f2bf(f3.w) << 16);
        unsigned short* q = nb + (size_t)(row0 + r) * DIM + col0 + c;
        *(uint4*)q = o0;
        *(uint4*)(q + 8) = o1;
    }
    __syncthreads();
    {
        unsigned short v[16];
#pragma unroll
        for (int u = 0; u < 16; ++u) v[u] = f2bf(tile[c + u][r]);
        unsigned short* q = tr + (size_t)(col0 + r) * N_T + row0 + c;
        *(uint4*)q = *(uint4*)&v[0];
        *(uint4*)(q + 8) = *(uint4*)&v[8];
    }
}

// ---- proj v3: fine-phase pipeline, 256x128 tiles, bias epilogue ------------
// C_bf16[4096][1024] = A_bf16 @ W_bf16^T + bias.  grid (16, 8, 2), 512 thr,
// 144 KB dynamic LDS -> 1 blk/CU. K=1024 -> 16 tiles: 14 staged + 2 peeled.
__global__ void __launch_bounds__(512)
gemm_proj3(const unsigned short* __restrict__ Atx, const unsigned short* __restrict__ Wtx,
           const float* __restrict__ btx, unsigned short* __restrict__ Ctx,
           const unsigned short* __restrict__ Aim, const unsigned short* __restrict__ Wim,
           const float* __restrict__ bim, unsigned short* __restrict__ Cim) {
    extern __shared__ unsigned short sm[];  // 3 * AT_SLOT shorts = 144 KB
    int z = blockIdx.z;
    const unsigned short* A = z ? Aim : Atx;
    const unsigned short* W = z ? Wim : Wtx;
    const float* bias = z ? bim : btx;
    unsigned short* C = z ? Cim : Ctx;

    int tid = threadIdx.x;
    int m0 = blockIdx.x * 256, n0 = blockIdx.y * 128;
    int lane = tid & 63, wave = tid >> 6;
    int lane16 = lane & 15, quad = lane >> 4;
    int wrow = (wave >> 1) * 64, wcol = (wave & 1) * 64;  // 4M x 2N waves
    f32x4 acc[4][4];
    {
        f32x4 zz = {0.f, 0.f, 0.f, 0.f};
        for (int i = 0; i < 4; ++i)
            for (int j = 0; j < 4; ++j) acc[i][j] = zz;
    }

    // prologue: slots 0,1 <- tiles 0,1; vmcnt(6) leaves tile 1's 6 newest.
    at_stageA<DIM>(A, m0, 0, sm, tid);
    at_stageB<DIM>(W, n0, 0, sm + 16384, tid);
    at_stageA<DIM>(A, m0, 64, sm + AT_SLOT, tid);
    at_stageB<DIM>(W, n0, 64, sm + AT_SLOT + 16384, tid);
    asm volatile("s_waitcnt vmcnt(6)" ::: "memory");
    __builtin_amdgcn_s_barrier();

    int cur = 0;
    for (int s = 0; s < 14; ++s) {  // DIM/64 - 2 pipelined tiles
        int ns = cur + 2; if (ns >= 3) ns -= 3;
        unsigned short* nsl = sm + ns * AT_SLOT;
        const unsigned short* cp = sm + cur * AT_SLOT;
        int kst = (s + 2) * 64;
        at_sub<DIM, 1>(cp, A, W, m0, n0, kst, nsl, tid, acc, wrow, wcol, lane16, quad, 0);
        asm volatile("" ::: "memory");
        __builtin_amdgcn_s_barrier();
        asm volatile("" ::: "memory");
        at_sub<DIM, 1>(cp, A, W, m0, n0, kst, nsl, tid, acc, wrow, wcol, lane16, quad, 1);
        asm volatile("s_waitcnt vmcnt(6) lgkmcnt(0)" ::: "memory");
        __builtin_amdgcn_s_barrier();
        cur += 1; if (cur >= 3) cur -= 3;
    }
    // tile 14 (no stage); end gate vmcnt(0): tile 15 fully landed.
    {
        const unsigned short* cp = sm + cur * AT_SLOT;
        at_sub<DIM, 0>(cp, A, W, m0, n0, 0, nullptr, tid, acc, wrow, wcol, lane16, quad, 0);
        asm volatile("" ::: "memory");
        __builtin_amdgcn_s_barrier();
        asm volatile("" ::: "memory");
        at_sub<DIM, 0>(cp, A, W, m0, n0, 0, nullptr, tid, acc, wrow, wcol, lane16, quad, 1);
        asm volatile("s_waitcnt vmcnt(0) lgkmcnt(0)" ::: "memory");
        __builtin_amdgcn_s_barrier();
        cur += 1; if (cur >= 3) cur -= 3;
    }
    // tile 15: compute only.
    {
        const unsigned short* cp = sm + cur * AT_SLOT;
        at_sub<DIM, 0>(cp, A, W, m0, n0, 0, nullptr, tid, acc, wrow, wcol, lane16, quad, 0);
        at_sub<DIM, 0>(cp, A, W, m0, n0, 0, nullptr, tid, acc, wrow, wcol, lane16, quad, 1);
    }

#pragma unroll
    for (int j = 0; j < 4; ++j) {
        int col = n0 + wcol + j * 16 + lane16;
        float bv = bias[col];
#pragma unroll
        for (int i = 0; i < 4; ++i) {
            int rowb = m0 + wrow + i * 16 + quad * 4;
#pragma unroll
            for (int r = 0; r < 4; ++r)
                C[(size_t)(rowb + r) * DIM + col] = f2bf(acc[i][j][r] + bv);
        }
    }
}

// ---- logits+exp v4: 256x128 tile, 512 thr, ~3 blk/CU -----------------------
// grid (16, 32) = 512 blocks. LDS 50.5 KB dynamic: K-buf A[256][64]+B[128][64]
// swizzled (48 KB, reused as [128][140] staging) + lred[256]/cred[3][128].
// Reads 384 MB (vs 512 at 128x128). Epilogue: P row-halves, PT col-halves,
// 1 atomic per row/col per block (r3-refcheck'd 8-wave reduction logic).
__global__ void __launch_bounds__(512)
gemm_logits_exp(const unsigned short* __restrict__ Tb,
                const unsigned short* __restrict__ Ib,
                unsigned short* __restrict__ P, unsigned short* __restrict__ PT,
                float* __restrict__ lT, float* __restrict__ lI) {
    extern __shared__ unsigned short sm[];
    float* lred = (float*)(sm + AT_SLOT);  // 256 floats (rows)
    float* cred = lred + 256;              // 3*128 floats (col bands 1..3)
    int tid = threadIdx.x;
    int m0 = blockIdx.x * 256, n0 = blockIdx.y * 128;
    int lane = tid & 63, wave = tid >> 6;
    int lane16 = lane & 15, quad = lane >> 4;
    int wrow = (wave >> 1) * 64, wcol = (wave & 1) * 64;  // 4M x 2N waves
    int half = wrow >> 7;                                  // 0: rows 0-127
    f32x4 acc[4][4];
    {
        f32x4 z = {0.f, 0.f, 0.f, 0.f};
        for (int i = 0; i < 4; ++i)
            for (int j = 0; j < 4; ++j) acc[i][j] = z;
    }
    // K-loop: single-buffered swizzled [256][64]+[128][64], 16 iterations.
    for (int k0 = 0; k0 < DIM; k0 += 64) {
        at_stageA<DIM>(Tb, m0, k0, sm, tid);
        at_stageB<DIM>(Ib, n0, k0, sm + 16384, tid);
        __syncthreads();
        at_sub<DIM, 0>(sm, nullptr, nullptr, 0, 0, 0, nullptr, tid, acc,
                       wrow, wcol, lane16, quad, 0);
        at_sub<DIM, 0>(sm, nullptr, nullptr, 0, 0, 0, nullptr, tid, acc,
                       wrow, wcol, lane16, quad, 1);
        __syncthreads();
    }
    // p = exp(logit/32) in place (fp32)
#pragma unroll
    for (int i = 0; i < 4; ++i)
#pragma unroll
        for (int j = 0; j < 4; ++j)
#pragma unroll
            for (int r = 0; r < 4; ++r)
                acc[i][j][r] = __expf(acc[i][j][r] * 0.03125f);
    // wave partials: rows (this wave's 64 cols) and cols (this wave's 64 rows)
    float rs[4][4];  // row partial, valid at lane16==0
#pragma unroll
    for (int i = 0; i < 4; ++i)
#pragma unroll
        for (int r = 0; r < 4; ++r) {
            float s = acc[i][0][r] + acc[i][1][r] + acc[i][2][r] + acc[i][3][r];
            s += __shfl_xor(s, 1); s += __shfl_xor(s, 2);
            s += __shfl_xor(s, 4); s += __shfl_xor(s, 8);
            rs[i][r] = s;
        }
    float cs[4];  // col partial, valid at quad==0
#pragma unroll
    for (int j = 0; j < 4; ++j) {
        float s = 0.f;
#pragma unroll
        for (int i = 0; i < 4; ++i)
#pragma unroll
            for (int r = 0; r < 4; ++r) s += acc[i][j][r];
        s += __shfl_xor(s, 16); s += __shfl_xor(s, 32);
        cs[j] = s;
    }
    int band = wave >> 1;
    // donors: odd wave of each row band -> lred; bands 1-3 -> cred slots.
    // Concurrently: waves 0-3 stage P rows 0-127 into [128][PSS].
    if (wave & 1) {
        if (lane16 == 0)
#pragma unroll
            for (int i = 0; i < 4; ++i)
#pragma unroll
                for (int r = 0; r < 4; ++r)
                    lred[wrow + i * 16 + quad * 4 + r] = rs[i][r];
    }
    if (band) {
        if (quad == 0)
#pragma unroll
            for (int j = 0; j < 4; ++j)
                cred[(band - 1) * 128 + wcol + j * 16 + lane16] = cs[j];
    }
    if (half == 0) {
#pragma unroll
        for (int i = 0; i < 4; ++i)
#pragma unroll
            for (int j = 0; j < 4; ++j)
#pragma unroll
                for (int r = 0; r < 4; ++r)
                    sm[(wrow + i * 16 + quad * 4 + r) * PSS + wcol + j * 16 + lane16] =
                        f2bf(acc[i][j][r]);
    }
    __syncthreads();
    // combiners: even wave finishes its band's rows; band 0 finishes cols.
    if (!(wave & 1) && lane16 == 0) {
#pragma unroll
        for (int i = 0; i < 4; ++i)
#pragma unroll
            for (int r = 0; r < 4; ++r) {
                int row = wrow + i * 16 + quad * 4 + r;
                atomicAdd(&lT[m0 + row], rs[i][r] + lred[row]);
            }
    }
    if (!band && quad == 0) {
#pragma unroll
        for (int j = 0; j < 4; ++j) {
            int c = wcol + j * 16 + lane16;
            atomicAdd(&lI[n0 + c], cs[j] + cred[c] + cred[128 + c] + cred[256 + c]);
        }
    }
    tile_store512(sm, P, N_I, m0, n0, tid);           // P rows 0-127
    __syncthreads();
    if (half == 1) {
#pragma unroll
        for (int i = 0; i < 4; ++i)
#pragma unroll
            for (int j = 0; j < 4; ++j)
#pragma unroll
                for (int r = 0; r < 4; ++r)
                    sm[(wrow - 128 + i * 16 + quad * 4 + r) * PSS + wcol + j * 16 + lane16] =
                        f2bf(acc[i][j][r]);
    }
    __syncthreads();
    tile_store512(sm, P, N_I, m0 + 128, n0, tid);     // P rows 128-255
    __syncthreads();
    // PT col-half 0: tile [128 n-rows][128 m-cols 0-127] from waves 0-3.
    if (half == 0) {
#pragma unroll
        for (int i = 0; i < 4; ++i)
#pragma unroll
            for (int j = 0; j < 4; ++j) {
                unsigned int lo = (unsigned int)f2bf(acc[i][j][0]) |
                                  ((unsigned int)f2bf(acc[i][j][1]) << 16);
                unsigned int hi = (unsigned int)f2bf(acc[i][j][2]) |
                                  ((unsigned int)f2bf(acc[i][j][3]) << 16);
                uint2 v; v.x = lo; v.y = hi;
                *(uint2*)&sm[(wcol + j * 16 + lane16) * PSS + wrow + i * 16 + quad * 4] = v;
            }
    }
    __syncthreads();
    tile_store512(sm, PT, N_T, n0, m0, tid);          // PT cols m0..m0+127
    __syncthreads();
    // PT col-half 1: m-cols 128-255 from waves 4-7.
    if (half == 1) {
#pragma unroll
        for (int i = 0; i < 4; ++i)
#pragma unroll
            for (int j = 0; j < 4; ++j) {
                unsigned int lo = (unsigned int)f2bf(acc[i][j][0]) |
                                  ((unsigned int)f2bf(acc[i][j][1]) << 16);
                unsigned int hi = (unsigned int)f2bf(acc[i][j][2]) |
                                  ((unsigned int)f2bf(acc[i][j][3]) << 16);
                uint2 v; v.x = lo; v.y = hi;
                *(uint2*)&sm[(wcol + j * 16 + lane16) * PSS + wrow - 128 + i * 16 + quad * 4] = v;
            }
    }
    __syncthreads();
    tile_store512(sm, PT, N_T, n0, m0 + 128, tid);    // PT cols m0+128..m0+255
}

// ---- attn v3 (r2-verified): fine-phase pipeline ----------------------------
// grid (16, 8, 2), 512 thr, 144 KB dynamic LDS -> 1 block/CU, 8 waves.
// Tile protocol: {sub0; barrier; sub1; vmcnt(6)+lgkmcnt(0); barrier}.
__global__ void __launch_bounds__(512)
gemm_attn3(const unsigned short* __restrict__ P, const unsigned short* __restrict__ imgT,
           const float* __restrict__ lT, const float* __restrict__ sTI,
           float* __restrict__ out0,
           const unsigned short* __restrict__ PT, const unsigned short* __restrict__ textT,
           const float* __restrict__ lI, const float* __restrict__ sIT,
           float* __restrict__ out1) {
    extern __shared__ unsigned short sm[];  // 3 * AT_SLOT shorts = 144 KB
    int which = blockIdx.z;
    const unsigned short* A = which ? PT : P;
    const unsigned short* Bt = which ? textT : imgT;
    const float* l = which ? lI : lT;
    const float* sp = which ? sIT : sTI;
    float* out = which ? out1 : out0;

    int tid = threadIdx.x;
    int m0 = blockIdx.x * 256, n0 = blockIdx.y * 128;
    int lane = tid & 63, wave = tid >> 6;
    int lane16 = lane & 15, quad = lane >> 4;
    int wrow = (wave >> 1) * 64, wcol = (wave & 1) * 64;  // 4M x 2N waves
    f32x4 acc[4][4];
    {
        f32x4 z = {0.f, 0.f, 0.f, 0.f};
        for (int i = 0; i < 4; ++i)
            for (int j = 0; j < 4; ++j) acc[i][j] = z;
    }

    // prologue: slots 0,1 <- tiles 0,1; vmcnt(6) leaves tile 1's 6 newest.
    at_stageA<4096>(A, m0, 0, sm, tid);
    at_stageB<4096>(Bt, n0, 0, sm + 16384, tid);
    at_stageA<4096>(A, m0, 64, sm + AT_SLOT, tid);
    at_stageB<4096>(Bt, n0, 64, sm + AT_SLOT + 16384, tid);
    asm volatile("s_waitcnt vmcnt(6)" ::: "memory");
    __builtin_amdgcn_s_barrier();

    int cur = 0;
    for (int s = 0; s < 62; ++s) {
        int ns = cur + 2; if (ns >= 3) ns -= 3;
        unsigned short* nsl = sm + ns * AT_SLOT;
        const unsigned short* cp = sm + cur * AT_SLOT;
        int kst = (s + 2) * 64;
        at_sub<4096, 1>(cp, A, Bt, m0, n0, kst, nsl, tid, acc, wrow, wcol, lane16, quad, 0);
        asm volatile("" ::: "memory");
        __builtin_amdgcn_s_barrier();
        asm volatile("" ::: "memory");
        at_sub<4096, 1>(cp, A, Bt, m0, n0, kst, nsl, tid, acc, wrow, wcol, lane16, quad, 1);
        asm volatile("s_waitcnt vmcnt(6) lgkmcnt(0)" ::: "memory");
        __builtin_amdgcn_s_barrier();
        cur += 1; if (cur >= 3) cur -= 3;
    }
    // tile 62 (no stage); end gate vmcnt(0): tile 63 fully landed.
    {
        const unsigned short* cp = sm + cur * AT_SLOT;
        at_sub<4096, 0>(cp, A, Bt, m0, n0, 0, nullptr, tid, acc, wrow, wcol, lane16, quad, 0);
        asm volatile("" ::: "memory");
        __builtin_amdgcn_s_barrier();
        asm volatile("" ::: "memory");
        at_sub<4096, 0>(cp, A, Bt, m0, n0, 0, nullptr, tid, acc, wrow, wcol, lane16, quad, 1);
        asm volatile("s_waitcnt vmcnt(0) lgkmcnt(0)" ::: "memory");
        __builtin_amdgcn_s_barrier();
        cur += 1; if (cur >= 3) cur -= 3;
    }
    // tile 63: compute only.
    {
        const unsigned short* cp = sm + cur * AT_SLOT;
        at_sub<4096, 0>(cp, A, Bt, m0, n0, 0, nullptr, tid, acc, wrow, wcol, lane16, quad, 0);
        at_sub<4096, 0>(cp, A, Bt, m0, n0, 0, nullptr, tid, acc, wrow, wcol, lane16, quad, 1);
    }

    float sc = sp[0];
#pragma unroll
    for (int i = 0; i < 4; ++i) {
        int rowb = m0 + wrow + i * 16 + quad * 4;
        float fac[4];
#pragma unroll
        for (int r = 0; r < 4; ++r) fac[r] = sc / l[rowb + r];
#pragma unroll
        for (int j = 0; j < 4; ++j) {
            int col = n0 + wcol + j * 16 + lane16;
#pragma unroll
            for (int r = 0; r < 4; ++r)
                out[(size_t)(rowb + r) * DIM + col] = acc[i][j][r] * fac[r];
        }
    }
}

extern "C" void kernel_launch(void* const* d_in, const int* in_sizes, int n_in,
                              void* d_out, int out_size, void* d_ws, size_t ws_size,
                              hipStream_t stream) {
    const float* text = (const float*)d_in[0];
    const float* image = (const float*)d_in[1];
    const float* w_text = (const float*)d_in[2];
    const float* b_text = (const float*)d_in[3];
    const float* w_image = (const float*)d_in[4];
    const float* b_image = (const float*)d_in[5];
    const float* scale_TI = (const float*)d_in[6];
    const float* scale_IT = (const float*)d_in[7];
    float* out0 = (float*)d_out;
    float* out1 = out0 + (size_t)N_T * DIM;

    // Workspace layout (96 MB + 32 KB). cvt buffers [0,20MB) die after proj;
    // gemm_logits_exp then writes P over [0,32MB) — lifetimes disjoint.
    char* ws = (char*)d_ws;
    unsigned short* text_bf = (unsigned short*)(ws);                 // 8 MB  (dies after proj)
    unsigned short* image_bf = (unsigned short*)(ws + (8ull << 20)); // 8 MB  (dies after proj)
    unsigned short* wt_bf = (unsigned short*)(ws + (16ull << 20));   // 2 MB  (dies after proj)
    unsigned short* wi_bf = (unsigned short*)(ws + (18ull << 20));   // 2 MB  (dies after proj)
    unsigned short* P = (unsigned short*)(ws);                       // 32 MB (logits -> attn)
    unsigned short* imgT = (unsigned short*)(ws + (32ull << 20));    // 8 MB
    unsigned short* textT = (unsigned short*)(ws + (40ull << 20));   // 8 MB
    unsigned short* t_bf = (unsigned short*)(ws + (48ull << 20));    // 8 MB
    unsigned short* i_bf = (unsigned short*)(ws + (56ull << 20));    // 8 MB
    unsigned short* PT = (unsigned short*)(ws + (64ull << 20));      // 32 MB
    float* lT = (float*)(ws + (96ull << 20));                        // 16 KB
    float* lI = (float*)(ws + (96ull << 20) + 16384);                // 16 KB

    // dynamic LDS attrs (one-time host attribute; safe under graph capture).
    static bool lds_set = false;
    if (!lds_set) {
        hipFuncSetAttribute((const void*)gemm_attn3,
                            hipFuncAttributeMaxDynamicSharedMemorySize, AT_LDS_BYTES);
        hipFuncSetAttribute((const void*)gemm_proj3,
                            hipFuncAttributeMaxDynamicSharedMemorySize, AT_LDS_BYTES);
        hipFuncSetAttribute((const void*)gemm_logits_exp,
                            hipFuncAttributeMaxDynamicSharedMemorySize, LG_LDS_BYTES);
        lds_set = true;
    }

    // z=0/1: feature 64x64 cvt+transpose tiles; z=2: weights cvt + lT/lI zero.
    cvt_all<<<dim3(N_T / 64, DIM / 64, 3), 256, 0, stream>>>(
        image, text, w_text, w_image, image_bf, text_bf, imgT, textT,
        wt_bf, wi_bf, lT);

    gemm_proj3<<<dim3(N_T / 256, DIM / 128, 2), 512, AT_LDS_BYTES, stream>>>(
        text_bf, wt_bf, b_text, t_bf, image_bf, wi_bf, b_image, i_bf);

    gemm_logits_exp<<<dim3(N_T / 256, N_I / 128), 512, LG_LDS_BYTES, stream>>>(
        t_bf, i_bf, P, PT, lT, lI);

    gemm_attn3<<<dim3(N_T / 256, DIM / 128, 2), 512, AT_LDS_BYTES, stream>>>(
        P, imgT, lT, scale_TI, out0, PT, textT, lI, scale_IT, out1);
}

// Round 9
// 246.768 us; speedup vs baseline: 1.0275x; 1.0275x over previous
//
#include <hip/hip_runtime.h>

// ---------------------------------------------------------------------------
// ImageTextModule: dual cross-attention between text and image feature sets.
//   t = text @ w_text^T + b_text ; i = image @ w_image^T + b_image  (bf16)
//   P  = exp((t @ i^T) / 32)  materialized ONCE in bf16, BOTH layouts (P, PT);
//        row/col exp-sums fused (1 atomic per row/col per block).
//   out0 = (scale_TI / lT) * P  @ image ; out1 = (scale_IT / lI) * PT @ text
// attn (v3, r2-verified): fine-phase counted-vmcnt pipeline. 256x128 tile,
//   512 thr / 8 waves; 3-slot LDS ring (144 KB dynamic); vmcnt(6)+lgkmcnt(0)
//   gate per tile; chunk16^=(row&7) swizzle both-sides -> conflicts 0.
//   68.2 µs = fabric floor (768 MB reads / ~11.5 TB/s). AT ROOFLINE for this
//   decomposition. FAILED (do not retry): A-from-global regs (r4: 158 µs);
//   XCD remap (r5: FETCH 98->139 MB, L3-fit broken).
// logits (v5, THIS round): r2 SHELL (128x128, 256 thr, 4 blk/CU, identical
//   epilogue) — r8's 256x128/512thr version regressed to 80 µs (occupancy/
//   serialization, read thpt 4.8 TB/s). Change: K-loop only. The r2 K-loop
//   drained vmcnt(0) every iter (m97 2-phase) -> read pipe idle -> 7.5 of
//   11.5 TB/s. Now: 2-slot BK=32 ring in the SAME 32 KB (As0/Bs0/As1/Bs1),
//   counted vmcnt(4) (never 0 mid-loop, T4) + [128][32] swizzle
//   chunk ^= (r+(r>>2))&3 both-sides (2-way max = free; T2 pays only in the
//   counted regime — r7 swizzle-alone was null, per regime gate).
// proj (v3, r6): attn3 pipeline at LD=1024, 16 K-tiles, bias epilogue.
// Workspace: 96 MB + 32 KB.
// ---------------------------------------------------------------------------

typedef __bf16 bf16x8 __attribute__((ext_vector_type(8)));
typedef float f32x4 __attribute__((ext_vector_type(4)));

#define N_T 4096
#define N_I 4096
#define DIM 1024
#define TSS 136  // logits epilogue tile stride (bf16): 128 + 8 pad

// attn/proj ring slot: A 256x64 bf16 (16384 sh) + B 128x64 bf16 (8192 sh)
#define AT_SLOT 24576
#define AT_LDS_BYTES (3 * AT_SLOT * 2)  // 147456 B = 144 KB

__device__ __forceinline__ unsigned short f2bf(float f) {
    unsigned int u = __float_as_uint(f);
    u += 0x7fffu + ((u >> 16) & 1u);  // RNE
    return (unsigned short)(u >> 16);
}

// 16-byte async global->LDS DMA (no VGPR round-trip).
__device__ __forceinline__ void async_cp16(const unsigned short* g, unsigned short* l) {
    __builtin_amdgcn_global_load_lds(
        (const __attribute__((address_space(1))) unsigned int*)g,
        (__attribute__((address_space(3))) unsigned int*)l, 16, 0, 0);
}

// Coalesced 128x128 bf16 tile store from LDS (stride TSS), 256 threads.
__device__ __forceinline__ void tile_store(const unsigned short* sm,
                                           unsigned short* __restrict__ g, int ld,
                                           int row0, int col0, int tid) {
    int r = tid >> 1, h = (tid & 1) << 6;
    const unsigned short* src = sm + r * TSS + h;
    unsigned short* dst = g + (size_t)(row0 + r) * ld + col0 + h;
#pragma unroll
    for (int v = 0; v < 8; ++v)
        *(uint4*)(dst + v * 8) = *(const uint4*)(src + v * 8);
}

// ---- logits K-loop helpers: [128][32] swizzled 2-slot ring -----------------
// LDS slot chunk q (16B) of row r holds GLOBAL chunk q ^ v32(r),
// v32(r) = (r + (r>>2)) & 3. Dest linear (rule 21: inverse-swizzle the DMA
// source, same XOR on the read). Frag reads: 2-way max bank alias (free).

// Stage 128x32 bf16 tile with 256 threads (2 cp16 each; v32(r+64)==v32(r)).
template <int LD>
__device__ __forceinline__ void stage_sw32(const unsigned short* __restrict__ src,
                                           int row0, int k0,
                                           unsigned short* lds, int t) {
    int r = t >> 2, q = t & 3;
    int kq = (q ^ ((r + (r >> 2)) & 3)) << 3;
    const unsigned short* g = src + (size_t)(row0 + r) * LD + k0;
    async_cp16(g + kq, lds + r * 32 + q * 8);
    async_cp16(g + (size_t)64 * LD + kq, lds + (64 + r) * 32 + q * 8);
}

// One BK=32 step on swizzled [128][32] tiles, 4x4 frags (64x64 wave tile).
// Read chunk = quad ^ v32(row); v32(row) == (lane16 + (lane16>>2)) & 3
// (wrow/wcol multiples of 64 and i*16 terms vanish mod 4).
__device__ __forceinline__ void mfma_sw32(const unsigned short* As,
                                          const unsigned short* Bs, f32x4 acc[4][4],
                                          int wrow, int wcol, int lane16, int quad) {
    bf16x8 a[4], b[4];
    int sw = (quad ^ ((lane16 + (lane16 >> 2)) & 3)) << 3;
#pragma unroll
    for (int i = 0; i < 4; ++i) {
        a[i] = *(const bf16x8*)&As[(wrow + i * 16 + lane16) * 32 + sw];
        b[i] = *(const bf16x8*)&Bs[(wcol + i * 16 + lane16) * 32 + sw];
    }
    __builtin_amdgcn_s_setprio(1);
#pragma unroll
    for (int i = 0; i < 4; ++i)
#pragma unroll
        for (int j = 0; j < 4; ++j)
            acc[i][j] = __builtin_amdgcn_mfma_f32_16x16x32_bf16(a[i], b[j], acc[i][j], 0, 0, 0);
    __builtin_amdgcn_s_setprio(0);
}

// ---- fine-phase pipeline stagers (attn + proj) -----------------------------
// Ring slot: A [256][64] bf16 (chunk16^=(row&7) swizzled), B [128][64].

// Stage A half h (128 rows, 1024 chunks, 2 per thread of 512; dest linear).
template <int LD>
__device__ __forceinline__ void at_stageA_half(const unsigned short* __restrict__ g,
                                               int row0, int k0, unsigned short* lds,
                                               int t, int h) {
#pragma unroll
    for (int u = 0; u < 2; ++u) {
        int c = t + (h * 2 + u) * 512;
        int r = c >> 3;
        int kq = (c & 7) ^ (r & 7);  // inverse-swizzled global chunk
        async_cp16(g + (size_t)(row0 + r) * LD + k0 + (kq << 3), lds + c * 8);
    }
}

// Stage B half h (64 rows, 512 chunks, 1 per thread).
template <int LD>
__device__ __forceinline__ void at_stageB_half(const unsigned short* __restrict__ g,
                                               int row0, int k0, unsigned short* lds,
                                               int t, int h) {
    int c = t + h * 512;
    int r = c >> 3;
    int kq = (c & 7) ^ (r & 7);
    async_cp16(g + (size_t)(row0 + r) * LD + k0 + (kq << 3), lds + c * 8);
}

// Full-tile stagers.
template <int LD>
__device__ __forceinline__ void at_stageA(const unsigned short* __restrict__ g,
                                          int row0, int k0, unsigned short* lds, int t) {
    at_stageA_half<LD>(g, row0, k0, lds, t, 0);
    at_stageA_half<LD>(g, row0, k0, lds, t, 1);
}
template <int LD>
__device__ __forceinline__ void at_stageB(const unsigned short* __restrict__ g,
                                          int row0, int k0, unsigned short* lds, int t) {
    at_stageB_half<LD>(g, row0, k0, lds, t, 0);
    at_stageB_half<LD>(g, row0, k0, lds, t, 1);
}

// One sub-phase: 8 swizzled ds_read_b128 (K-slice ks of slot cp) + optional
// stage-half ks of a later tile into nsl + 16 MFMA under setprio(1).
template <int LD, int DO_STAGE>
__device__ __forceinline__ void at_sub(const unsigned short* cp,
                                       const unsigned short* __restrict__ A,
                                       const unsigned short* __restrict__ Bt,
                                       int m0, int n0, int kst, unsigned short* nsl,
                                       int t, f32x4 acc[4][4],
                                       int wrow, int wcol, int lane16, int quad, int ks) {
    const unsigned short* As = cp;
    const unsigned short* Bs = cp + 16384;
    bf16x8 a[4], b[4];
    int sw = (((ks << 2) | quad) ^ (lane16 & 7)) << 3;  // row&7 == lane16&7
#pragma unroll
    for (int i = 0; i < 4; ++i)
        a[i] = *(const bf16x8*)&As[(wrow + i * 16 + lane16) * 64 + sw];
#pragma unroll
    for (int j = 0; j < 4; ++j)
        b[j] = *(const bf16x8*)&Bs[(wcol + j * 16 + lane16) * 64 + sw];
    if (DO_STAGE) {
        at_stageA_half<LD>(A, m0, kst, nsl, t, ks);
        at_stageB_half<LD>(Bt, n0, kst, nsl + 16384, t, ks);
    }
    __builtin_amdgcn_s_setprio(1);
#pragma unroll
    for (int i = 0; i < 4; ++i)
#pragma unroll
        for (int j = 0; j < 4; ++j)
            acc[i][j] = __builtin_amdgcn_mfma_f32_16x16x32_bf16(a[i], b[j], acc[i][j], 0, 0, 0);
    __builtin_amdgcn_s_setprio(0);
}

// ---- unified pre-pass ------------------------------------------------------
// z=0: image 64x64 tile -> image_bf + imgT      z=1: text -> text_bf + textT
// z=2: weights flat cvt (lin id over 1024 blocks); blocks 0-3 zero lT/lI.
__global__ void __launch_bounds__(256)
cvt_all(const float* __restrict__ im, const float* __restrict__ tx,
        const float* __restrict__ wt, const float* __restrict__ wi,
        unsigned short* __restrict__ imb, unsigned short* __restrict__ txb,
        unsigned short* __restrict__ imgT, unsigned short* __restrict__ textT,
        unsigned short* __restrict__ wtb, unsigned short* __restrict__ wib,
        float* __restrict__ lTI) {
    int t = threadIdx.x;
    if (blockIdx.z == 2) {
        int lin = blockIdx.y * 64 + blockIdx.x;  // 0..1023
        if (lin < 4) {
            *(f32x4*)&lTI[(lin * 256 + t) * 8] = (f32x4){0.f, 0.f, 0.f, 0.f};
            *(f32x4*)&lTI[(lin * 256 + t) * 8 + 4] = (f32x4){0.f, 0.f, 0.f, 0.f};
        }
        size_t i = (size_t)(lin * 256 + t) * 8;
        const float* s;
        unsigned short* d;
        size_t off;
        if (i < 1048576) { s = wt; d = wtb; off = i; }
        else             { s = wi; d = wib; off = i - 1048576; }
        float4 f0 = *(const float4*)(s + off);
        float4 f1 = *(const float4*)(s + off + 4);
        uint4 o;
        o.x = (unsigned int)f2bf(f0.x) | ((unsigned int)f2bf(f0.y) << 16);
        o.y = (unsigned int)f2bf(f0.z) | ((unsigned int)f2bf(f0.w) << 16);
        o.z = (unsigned int)f2bf(f1.x) | ((unsigned int)f2bf(f1.y) << 16);
        o.w = (unsigned int)f2bf(f1.z) | ((unsigned int)f2bf(f1.w) << 16);
        *(uint4*)(d + off) = o;
        return;
    }
    const float* in = blockIdx.z ? tx : im;
    unsigned short* nb = blockIdx.z ? txb : imb;
    unsigned short* tr = blockIdx.z ? textT : imgT;
    __shared__ float tile[64][65];
    int row0 = blockIdx.x * 64, col0 = blockIdx.y * 64;
    int r = t >> 2, c = (t & 3) << 4;  // 64 rows x 4 col-chunks of 16
    {
        const float* p = in + (size_t)(row0 + r) * DIM + col0 + c;
        float4 f0 = *(const float4*)(p);
        float4 f1 = *(const float4*)(p + 4);
        float4 f2 = *(const float4*)(p + 8);
        float4 f3 = *(const float4*)(p + 12);
        *(float4*)&tile[r][c] = f0;
        *(float4*)&tile[r][c + 4] = f1;
        *(float4*)&tile[r][c + 8] = f2;
        *(float4*)&tile[r][c + 12] = f3;
        uint4 o0, o1;
        o0.x = (unsigned int)f2bf(f0.x) | ((unsigned int)f2bf(f0.y) << 16);
        o0.y = (unsigned int)f2bf(f0.z) | ((unsigned int)f2bf(f0.w) << 16);
        o0.z = (unsigned int)f2bf(f1.x) | ((unsigned int)f2bf(f1.y) << 16);
        o0.w = (unsigned int)f2bf(f1.z) | ((unsigned int)f2bf(f1.w) << 16);
        o1.x = (unsigned int)f2bf(f2.x) | ((unsigned int)f2bf(f2.y) << 16);
        o1.y = (unsigned int)f2bf(f2.z) | ((unsigned int)f2bf(f2.w) << 16);
        o1.z = (unsigned int)f2bf(f3.x) | ((unsigned int)f2bf(f3.y) << 16);
        o1.w = (unsigned int)f2bf(f3.z) | ((unsigned int)f2bf(f3.w) << 16);
        unsigned short* q = nb + (size_t)(row0 + r) * DIM + col0 + c;
        *(uint4*)q = o0;
        *(uint4*)(q + 8) = o1;
    }
    __syncthreads();
    {
        unsigned short v[16];
#pragma unroll
        for (int u = 0; u < 16; ++u) v[u] = f2bf(tile[c + u][r]);
        unsigned short* q = tr + (size_t)(col0 + r) * N_T + row0 + c;
        *(uint4*)q = *(uint4*)&v[0];
        *(uint4*)(q + 8) = *(uint4*)&v[8];
    }
}

// ---- proj v3: fine-phase pipeline, 256x128 tiles, bias epilogue ------------
// C_bf16[4096][1024] = A_bf16 @ W_bf16^T + bias.  grid (16, 8, 2), 512 thr,
// 144 KB dynamic LDS -> 1 blk/CU. K=1024 -> 16 tiles: 14 staged + 2 peeled.
__global__ void __launch_bounds__(512)
gemm_proj3(const unsigned short* __restrict__ Atx, const unsigned short* __restrict__ Wtx,
           const float* __restrict__ btx, unsigned short* __restrict__ Ctx,
           const unsigned short* __restrict__ Aim, const unsigned short* __restrict__ Wim,
           const float* __restrict__ bim, unsigned short* __restrict__ Cim) {
    extern __shared__ unsigned short sm[];  // 3 * AT_SLOT shorts = 144 KB
    int z = blockIdx.z;
    const unsigned short* A = z ? Aim : Atx;
    const unsigned short* W = z ? Wim : Wtx;
    const float* bias = z ? bim : btx;
    unsigned short* C = z ? Cim : Ctx;

    int tid = threadIdx.x;
    int m0 = blockIdx.x * 256, n0 = blockIdx.y * 128;
    int lane = tid & 63, wave = tid >> 6;
    int lane16 = lane & 15, quad = lane >> 4;
    int wrow = (wave >> 1) * 64, wcol = (wave & 1) * 64;  // 4M x 2N waves
    f32x4 acc[4][4];
    {
        f32x4 zz = {0.f, 0.f, 0.f, 0.f};
        for (int i = 0; i < 4; ++i)
            for (int j = 0; j < 4; ++j) acc[i][j] = zz;
    }

    // prologue: slots 0,1 <- tiles 0,1; vmcnt(6) leaves tile 1's 6 newest.
    at_stageA<DIM>(A, m0, 0, sm, tid);
    at_stageB<DIM>(W, n0, 0, sm + 16384, tid);
    at_stageA<DIM>(A, m0, 64, sm + AT_SLOT, tid);
    at_stageB<DIM>(W, n0, 64, sm + AT_SLOT + 16384, tid);
    asm volatile("s_waitcnt vmcnt(6)" ::: "memory");
    __builtin_amdgcn_s_barrier();

    int cur = 0;
    for (int s = 0; s < 14; ++s) {  // DIM/64 - 2 pipelined tiles
        int ns = cur + 2; if (ns >= 3) ns -= 3;
        unsigned short* nsl = sm + ns * AT_SLOT;
        const unsigned short* cp = sm + cur * AT_SLOT;
        int kst = (s + 2) * 64;
        at_sub<DIM, 1>(cp, A, W, m0, n0, kst, nsl, tid, acc, wrow, wcol, lane16, quad, 0);
        asm volatile("" ::: "memory");
        __builtin_amdgcn_s_barrier();
        asm volatile("" ::: "memory");
        at_sub<DIM, 1>(cp, A, W, m0, n0, kst, nsl, tid, acc, wrow, wcol, lane16, quad, 1);
        asm volatile("s_waitcnt vmcnt(6) lgkmcnt(0)" ::: "memory");
        __builtin_amdgcn_s_barrier();
        cur += 1; if (cur >= 3) cur -= 3;
    }
    // tile 14 (no stage); end gate vmcnt(0): tile 15 fully landed.
    {
        const unsigned short* cp = sm + cur * AT_SLOT;
        at_sub<DIM, 0>(cp, A, W, m0, n0, 0, nullptr, tid, acc, wrow, wcol, lane16, quad, 0);
        asm volatile("" ::: "memory");
        __builtin_amdgcn_s_barrier();
        asm volatile("" ::: "memory");
        at_sub<DIM, 0>(cp, A, W, m0, n0, 0, nullptr, tid, acc, wrow, wcol, lane16, quad, 1);
        asm volatile("s_waitcnt vmcnt(0) lgkmcnt(0)" ::: "memory");
        __builtin_amdgcn_s_barrier();
        cur += 1; if (cur >= 3) cur -= 3;
    }
    // tile 15: compute only.
    {
        const unsigned short* cp = sm + cur * AT_SLOT;
        at_sub<DIM, 0>(cp, A, W, m0, n0, 0, nullptr, tid, acc, wrow, wcol, lane16, quad, 0);
        at_sub<DIM, 0>(cp, A, W, m0, n0, 0, nullptr, tid, acc, wrow, wcol, lane16, quad, 1);
    }

#pragma unroll
    for (int j = 0; j < 4; ++j) {
        int col = n0 + wcol + j * 16 + lane16;
        float bv = bias[col];
#pragma unroll
        for (int i = 0; i < 4; ++i) {
            int rowb = m0 + wrow + i * 16 + quad * 4;
#pragma unroll
            for (int r = 0; r < 4; ++r)
                C[(size_t)(rowb + r) * DIM + col] = f2bf(acc[i][j][r] + bv);
        }
    }
}

// ---- logits+exp v5: counted-vmcnt BK=32 ring in the r2 shell ---------------
// 128x128 tile, 256 thr, 4 blk/CU. K-loop: 2-slot ring (As0/Bs0 | As1/Bs1,
// same 32 KB as r2), stage s+1 while computing s, gate vmcnt(4) (the 4 just-
// issued cp16 stay in flight; stage s landed) — reads never drain mid-loop.
// Epilogue byte-identical to r2 (refcheck'd, absmax 4.88e-4).
__global__ void __launch_bounds__(256, 4)
gemm_logits_exp(const unsigned short* __restrict__ Tb,
                const unsigned short* __restrict__ Ib,
                unsigned short* __restrict__ P, unsigned short* __restrict__ PT,
                float* __restrict__ lT, float* __restrict__ lI) {
    __shared__ unsigned short smem[128 * TSS];  // 34.8 KB: K-bufs + epilogue
    unsigned short* As0 = smem;
    unsigned short* Bs0 = smem + 4096;
    unsigned short* As1 = smem + 8192;
    unsigned short* Bs1 = smem + 12288;
    float* lred = (float*)(smem + 16384);  // 128 floats (free tail of smem)
    float* cred = lred + 128;              // 128 floats
    int tid = threadIdx.x;
    int m0 = blockIdx.x * 128, n0 = blockIdx.y * 128;
    int lane = tid & 63, wave = tid >> 6;
    int lane16 = lane & 15, quad = lane >> 4;
    int wrow = (wave >> 1) * 64, wcol = (wave & 1) * 64;
    f32x4 acc[4][4];
    {
        f32x4 z = {0.f, 0.f, 0.f, 0.f};
        for (int i = 0; i < 4; ++i)
            for (int j = 0; j < 4; ++j) acc[i][j] = z;
    }
    // K-loop: 32 BK=32 tiles; tile s lives in buf s&1.
    stage_sw32<DIM>(Tb, m0, 0, As0, tid);
    stage_sw32<DIM>(Ib, n0, 0, Bs0, tid);
    for (int s = 0; s < 31; ++s) {
        unsigned short* nA = (s & 1) ? As0 : As1;
        unsigned short* nB = (s & 1) ? Bs0 : Bs1;
        const unsigned short* cA = (s & 1) ? As1 : As0;
        const unsigned short* cB = (s & 1) ? Bs1 : Bs0;
        stage_sw32<DIM>(Tb, m0, (s + 1) * 32, nA, tid);
        stage_sw32<DIM>(Ib, n0, (s + 1) * 32, nB, tid);
        asm volatile("s_waitcnt vmcnt(4)" ::: "memory");  // tile s landed
        __builtin_amdgcn_s_barrier();
        mfma_sw32(cA, cB, acc, wrow, wcol, lane16, quad);
        asm volatile("s_waitcnt lgkmcnt(0)" ::: "memory");  // buf reads retired
        __builtin_amdgcn_s_barrier();
    }
    // tile 31 (buf 1): drain and compute.
    asm volatile("s_waitcnt vmcnt(0)" ::: "memory");
    __builtin_amdgcn_s_barrier();
    mfma_sw32(As1, Bs1, acc, wrow, wcol, lane16, quad);
    // p = exp(logit/32) in place (fp32)
#pragma unroll
    for (int i = 0; i < 4; ++i)
#pragma unroll
        for (int j = 0; j < 4; ++j)
#pragma unroll
            for (int r = 0; r < 4; ++r)
                acc[i][j][r] = __expf(acc[i][j][r] * 0.03125f);
    // wave partials: rows (this wave's 64 cols) and cols (this wave's 64 rows)
    float rs[4][4];  // row partial, valid at lane16==0
#pragma unroll
    for (int i = 0; i < 4; ++i)
#pragma unroll
        for (int r = 0; r < 4; ++r) {
            float s = acc[i][0][r] + acc[i][1][r] + acc[i][2][r] + acc[i][3][r];
            s += __shfl_xor(s, 1); s += __shfl_xor(s, 2);
            s += __shfl_xor(s, 4); s += __shfl_xor(s, 8);
            rs[i][r] = s;
        }
    float cs[4];  // col partial, valid at quad==0
#pragma unroll
    for (int j = 0; j < 4; ++j) {
        float s = 0.f;
#pragma unroll
        for (int i = 0; i < 4; ++i)
#pragma unroll
            for (int r = 0; r < 4; ++r) s += acc[i][j][r];
        s += __shfl_xor(s, 16); s += __shfl_xor(s, 32);
        cs[j] = s;
    }
    // donors: waves 1,3 stash row partials; waves 2,3 stash col partials
    if (wave & 1) {
        if (lane16 == 0)
#pragma unroll
            for (int i = 0; i < 4; ++i)
#pragma unroll
                for (int r = 0; r < 4; ++r)
                    lred[wrow + i * 16 + quad * 4 + r] = rs[i][r];
    }
    if (wave >> 1) {
        if (quad == 0)
#pragma unroll
            for (int j = 0; j < 4; ++j)
                cred[wcol + j * 16 + lane16] = cs[j];
    }
    __syncthreads();
    // combiners: waves 0,2 finish rows; waves 0,1 finish cols
    if (!(wave & 1) && lane16 == 0) {
#pragma unroll
        for (int i = 0; i < 4; ++i)
#pragma unroll
            for (int r = 0; r < 4; ++r) {
                int row = wrow + i * 16 + quad * 4 + r;
                atomicAdd(&lT[m0 + row], rs[i][r] + lred[row]);
            }
    }
    if (!(wave >> 1) && quad == 0) {
#pragma unroll
        for (int j = 0; j < 4; ++j) {
            int col = wcol + j * 16 + lane16;
            atomicAdd(&lI[n0 + col], cs[j] + cred[col]);
        }
    }
    // pass 1: normal-layout tile -> P (coalesced b128 stores)
    __syncthreads();
#pragma unroll
    for (int i = 0; i < 4; ++i)
#pragma unroll
        for (int j = 0; j < 4; ++j)
#pragma unroll
            for (int r = 0; r < 4; ++r)
                smem[(wrow + i * 16 + quad * 4 + r) * TSS + wcol + j * 16 + lane16] =
                    f2bf(acc[i][j][r]);
    __syncthreads();
    tile_store(smem, P, N_I, m0, n0, tid);
    // pass 2: transposed tile -> PT (b64 LDS writes, coalesced b128 stores)
    __syncthreads();
#pragma unroll
    for (int i = 0; i < 4; ++i)
#pragma unroll
        for (int j = 0; j < 4; ++j) {
            unsigned int lo = (unsigned int)f2bf(acc[i][j][0]) |
                              ((unsigned int)f2bf(acc[i][j][1]) << 16);
            unsigned int hi = (unsigned int)f2bf(acc[i][j][2]) |
                              ((unsigned int)f2bf(acc[i][j][3]) << 16);
            uint2 v; v.x = lo; v.y = hi;
            *(uint2*)&smem[(wcol + j * 16 + lane16) * TSS + wrow + i * 16 + quad * 4] = v;
        }
    __syncthreads();
    tile_store(smem, PT, N_T, n0, m0, tid);
}

// ---- attn v3 (r2-verified): fine-phase pipeline ----------------------------
// grid (16, 8, 2), 512 thr, 144 KB dynamic LDS -> 1 block/CU, 8 waves.
// Tile protocol: {sub0; barrier; sub1; vmcnt(6)+lgkmcnt(0); barrier}.
__global__ void __launch_bounds__(512)
gemm_attn3(const unsigned short* __restrict__ P, const unsigned short* __restrict__ imgT,
           const float* __restrict__ lT, const float* __restrict__ sTI,
           float* __restrict__ out0,
           const unsigned short* __restrict__ PT, const unsigned short* __restrict__ textT,
           const float* __restrict__ lI, const float* __restrict__ sIT,
           float* __restrict__ out1) {
    extern __shared__ unsigned short sm[];  // 3 * AT_SLOT shorts = 144 KB
    int which = blockIdx.z;
    const unsigned short* A = which ? PT : P;
    const unsigned short* Bt = which ? textT : imgT;
    const float* l = which ? lI : lT;
    const float* sp = which ? sIT : sTI;
    float* out = which ? out1 : out0;

    int tid = threadIdx.x;
    int m0 = blockIdx.x * 256, n0 = blockIdx.y * 128;
    int lane = tid & 63, wave = tid >> 6;
    int lane16 = lane & 15, quad = lane >> 4;
    int wrow = (wave >> 1) * 64, wcol = (wave & 1) * 64;  // 4M x 2N waves
    f32x4 acc[4][4];
    {
        f32x4 z = {0.f, 0.f, 0.f, 0.f};
        for (int i = 0; i < 4; ++i)
            for (int j = 0; j < 4; ++j) acc[i][j] = z;
    }

    // prologue: slots 0,1 <- tiles 0,1; vmcnt(6) leaves tile 1's 6 newest.
    at_stageA<4096>(A, m0, 0, sm, tid);
    at_stageB<4096>(Bt, n0, 0, sm + 16384, tid);
    at_stageA<4096>(A, m0, 64, sm + AT_SLOT, tid);
    at_stageB<4096>(Bt, n0, 64, sm + AT_SLOT + 16384, tid);
    asm volatile("s_waitcnt vmcnt(6)" ::: "memory");
    __builtin_amdgcn_s_barrier();

    int cur = 0;
    for (int s = 0; s < 62; ++s) {
        int ns = cur + 2; if (ns >= 3) ns -= 3;
        unsigned short* nsl = sm + ns * AT_SLOT;
        const unsigned short* cp = sm + cur * AT_SLOT;
        int kst = (s + 2) * 64;
        at_sub<4096, 1>(cp, A, Bt, m0, n0, kst, nsl, tid, acc, wrow, wcol, lane16, quad, 0);
        asm volatile("" ::: "memory");
        __builtin_amdgcn_s_barrier();
        asm volatile("" ::: "memory");
        at_sub<4096, 1>(cp, A, Bt, m0, n0, kst, nsl, tid, acc, wrow, wcol, lane16, quad, 1);
        asm volatile("s_waitcnt vmcnt(6) lgkmcnt(0)" ::: "memory");
        __builtin_amdgcn_s_barrier();
        cur += 1; if (cur >= 3) cur -= 3;
    }
    // tile 62 (no stage); end gate vmcnt(0): tile 63 fully landed.
    {
        const unsigned short* cp = sm + cur * AT_SLOT;
        at_sub<4096, 0>(cp, A, Bt, m0, n0, 0, nullptr, tid, acc, wrow, wcol, lane16, quad, 0);
        asm volatile("" ::: "memory");
        __builtin_amdgcn_s_barrier();
        asm volatile("" ::: "memory");
        at_sub<4096, 0>(cp, A, Bt, m0, n0, 0, nullptr, tid, acc, wrow, wcol, lane16, quad, 1);
        asm volatile("s_waitcnt vmcnt(0) lgkmcnt(0)" ::: "memory");
        __builtin_amdgcn_s_barrier();
        cur += 1; if (cur >= 3) cur -= 3;
    }
    // tile 63: compute only.
    {
        const unsigned short* cp = sm + cur * AT_SLOT;
        at_sub<4096, 0>(cp, A, Bt, m0, n0, 0, nullptr, tid, acc, wrow, wcol, lane16, quad, 0);
        at_sub<4096, 0>(cp, A, Bt, m0, n0, 0, nullptr, tid, acc, wrow, wcol, lane16, quad, 1);
    }

    float sc = sp[0];
#pragma unroll
    for (int i = 0; i < 4; ++i) {
        int rowb = m0 + wrow + i * 16 + quad * 4;
        float fac[4];
#pragma unroll
        for (int r = 0; r < 4; ++r) fac[r] = sc / l[rowb + r];
#pragma unroll
        for (int j = 0; j < 4; ++j) {
            int col = n0 + wcol + j * 16 + lane16;
#pragma unroll
            for (int r = 0; r < 4; ++r)
                out[(size_t)(rowb + r) * DIM + col] = acc[i][j][r] * fac[r];
        }
    }
}

extern "C" void kernel_launch(void* const* d_in, const int* in_sizes, int n_in,
                              void* d_out, int out_size, void* d_ws, size_t ws_size,
                              hipStream_t stream) {
    const float* text = (const float*)d_in[0];
    const float* image = (const float*)d_in[1];
    const float* w_text = (const float*)d_in[2];
    const float* b_text = (const float*)d_in[3];
    const float* w_image = (const float*)d_in[4];
    const float* b_image = (const float*)d_in[5];
    const float* scale_TI = (const float*)d_in[6];
    const float* scale_IT = (const float*)d_in[7];
    float* out0 = (float*)d_out;
    float* out1 = out0 + (size_t)N_T * DIM;

    // Workspace layout (96 MB + 32 KB). cvt buffers [0,20MB) die after proj;
    // gemm_logits_exp then writes P over [0,32MB) — lifetimes disjoint.
    char* ws = (char*)d_ws;
    unsigned short* text_bf = (unsigned short*)(ws);                 // 8 MB  (dies after proj)
    unsigned short* image_bf = (unsigned short*)(ws + (8ull << 20)); // 8 MB  (dies after proj)
    unsigned short* wt_bf = (unsigned short*)(ws + (16ull << 20));   // 2 MB  (dies after proj)
    unsigned short* wi_bf = (unsigned short*)(ws + (18ull << 20));   // 2 MB  (dies after proj)
    unsigned short* P = (unsigned short*)(ws);                       // 32 MB (logits -> attn)
    unsigned short* imgT = (unsigned short*)(ws + (32ull << 20));    // 8 MB
    unsigned short* textT = (unsigned short*)(ws + (40ull << 20));   // 8 MB
    unsigned short* t_bf = (unsigned short*)(ws + (48ull << 20));    // 8 MB
    unsigned short* i_bf = (unsigned short*)(ws + (56ull << 20));    // 8 MB
    unsigned short* PT = (unsigned short*)(ws + (64ull << 20));      // 32 MB
    float* lT = (float*)(ws + (96ull << 20));                        // 16 KB
    float* lI = (float*)(ws + (96ull << 20) + 16384);                // 16 KB

    // 144 KB dynamic LDS (one-time host attribute; safe under graph capture).
    static bool lds_set = false;
    if (!lds_set) {
        hipFuncSetAttribute((const void*)gemm_attn3,
                            hipFuncAttributeMaxDynamicSharedMemorySize, AT_LDS_BYTES);
        hipFuncSetAttribute((const void*)gemm_proj3,
                            hipFuncAttributeMaxDynamicSharedMemorySize, AT_LDS_BYTES);
        lds_set = true;
    }

    // z=0/1: feature 64x64 cvt+transpose tiles; z=2: weights cvt + lT/lI zero.
    cvt_all<<<dim3(N_T / 64, DIM / 64, 3), 256, 0, stream>>>(
        image, text, w_text, w_image, image_bf, text_bf, imgT, textT,
        wt_bf, wi_bf, lT);

    gemm_proj3<<<dim3(N_T / 256, DIM / 128, 2), 512, AT_LDS_BYTES, stream>>>(
        text_bf, wt_bf, b_text, t_bf, image_bf, wi_bf, b_image, i_bf);

    gemm_logits_exp<<<dim3(N_T / 128, N_I / 128), 256, 0, stream>>>(t_bf, i_bf, P, PT, lT, lI);

    gemm_attn3<<<dim3(N_T / 256, DIM / 128, 2), 512, AT_LDS_BYTES, stream>>>(
        P, imgT, lT, scale_TI, out0, PT, textT, lI, scale_IT, out1);
}

// Round 10
// 238.797 us; speedup vs baseline: 1.0618x; 1.0334x over previous
//
#include <hip/hip_runtime.h>

// ---------------------------------------------------------------------------
// ImageTextModule: dual cross-attention between text and image feature sets.
//   t = text @ w_text^T + b_text ; i = image @ w_image^T + b_image  (bf16)
//   P  = exp((t @ i^T) / 32)  materialized ONCE in bf16, BOTH layouts (P, PT);
//        row/col exp-sums fused (1 atomic per row/col per block).
//   out0 = (scale_TI / lT) * P  @ image ; out1 = (scale_IT / lI) * PT @ text
// BEST-KNOWN CONFIG (round-6 result, 245.6 µs) restored verbatim.
// attn (v3, r2-verified): fine-phase counted-vmcnt pipeline. 256x128 tile,
//   512 thr / 8 waves; 3-slot LDS ring (144 KB dynamic); vmcnt(6)+lgkmcnt(0)
//   gate per tile; chunk16^=(row&7) swizzle both-sides -> conflicts 0.
//   68.2 µs = fabric floor (768 MB reads / 11.3 TB/s, reproduced 3x).
//   FAILED (do not retry): A-from-global regs (r4: 158 µs); XCD remap
//   (r5: FETCH 98->139 MB — L3-fit, remap breaks sharing).
// logits (r2-exact): 128x128, 256 thr, 4 blk/CU, 4-buffer BK=64 K-loop.
//   ~68 µs = serial-chain floor (K-loop read-stream ~44 + epilogue ~25,
//   partially overlapped at 4 blk/CU). ALL levers null/negative: T2 swizzle
//   (r7: null — 2-phase regime hides conflicts), 256x128 tile (r8: 80 µs,
//   occupancy), counted-vmcnt BK=32 ring (r9: null, 2-way conflicts free).
//   Do not re-attack without a new mechanism.
// proj (v3, r6): attn3 pipeline at LD=1024, 16 K-tiles, bias epilogue.
// Ledger: total - attn - logits ≈ 105-110 µs constant across all 10 rounds
// (cvt ~18 + proj ~13 + fixed overhead) — invariant to kernel rewrites.
// Workspace: 96 MB + 32 KB.
// ---------------------------------------------------------------------------

typedef __bf16 bf16x8 __attribute__((ext_vector_type(8)));
typedef float f32x4 __attribute__((ext_vector_type(4)));

#define N_T 4096
#define N_I 4096
#define DIM 1024
#define TSS 136  // logits epilogue tile stride (bf16): 128 + 8 pad

// ring slot: A 256x64 bf16 (16384 sh) + B 128x64 bf16 (8192 sh) = 48 KB
#define AT_SLOT 24576
#define AT_LDS_BYTES (3 * AT_SLOT * 2)  // 147456 B = 144 KB

__device__ __forceinline__ unsigned short f2bf(float f) {
    unsigned int u = __float_as_uint(f);
    u += 0x7fffu + ((u >> 16) & 1u);  // RNE
    return (unsigned short)(u >> 16);
}

// 16-byte async global->LDS DMA (no VGPR round-trip).
__device__ __forceinline__ void async_cp16(const unsigned short* g, unsigned short* l) {
    __builtin_amdgcn_global_load_lds(
        (const __attribute__((address_space(1))) unsigned int*)g,
        (__attribute__((address_space(3))) unsigned int*)l, 16, 0, 0);
}

// Stage 128x32 bf16 tile -> unpadded LDS [128][32] with 256 threads.
__device__ __forceinline__ void stage_async(const unsigned short* __restrict__ src,
                                            int ld, int row0, int k0,
                                            unsigned short* lds, int t) {
    int r = t >> 2, c = (t & 3) << 3;
    const unsigned short* g = src + (size_t)(row0 + r) * ld + k0 + c;
    async_cp16(g, lds + r * 32 + c);
    async_cp16(g + (size_t)64 * ld, lds + (64 + r) * 32 + c);
}

// One BK=32 MFMA step, 4x4 frags (64x64 wave tile) — logits kernel.
__device__ __forceinline__ void mfma_step(const unsigned short* As,
                                          const unsigned short* Bs, f32x4 acc[4][4],
                                          int wrow, int wcol, int lane16, int quad) {
    bf16x8 a[4], b[4];
#pragma unroll
    for (int i = 0; i < 4; ++i) {
        a[i] = *(const bf16x8*)&As[(wrow + i * 16 + lane16) * 32 + quad * 8];
        b[i] = *(const bf16x8*)&Bs[(wcol + i * 16 + lane16) * 32 + quad * 8];
    }
#pragma unroll
    for (int i = 0; i < 4; ++i)
#pragma unroll
        for (int j = 0; j < 4; ++j)
            acc[i][j] = __builtin_amdgcn_mfma_f32_16x16x32_bf16(a[i], b[j], acc[i][j], 0, 0, 0);
}

// Coalesced 128x128 bf16 tile store from LDS (stride TSS) to global.
__device__ __forceinline__ void tile_store(const unsigned short* sm,
                                           unsigned short* __restrict__ g, int ld,
                                           int row0, int col0, int tid) {
    int r = tid >> 1, h = (tid & 1) << 6;
    const unsigned short* src = sm + r * TSS + h;
    unsigned short* dst = g + (size_t)(row0 + r) * ld + col0 + h;
#pragma unroll
    for (int v = 0; v < 8; ++v)
        *(uint4*)(dst + v * 8) = *(const uint4*)(src + v * 8);
}

// ---- fine-phase pipeline stagers (attn + proj) -----------------------------
// Ring slot: A [256][64] bf16 (chunk16^=(row&7) swizzled), B [128][64].
// Swizzle applied BOTH at the gload source (inverse) and ds_read addr
// (rule 21) -> conflict-free (measured 0).

// Stage A half h (128 rows, 1024 chunks, 2 per thread of 512; dest linear).
template <int LD>
__device__ __forceinline__ void at_stageA_half(const unsigned short* __restrict__ g,
                                               int row0, int k0, unsigned short* lds,
                                               int t, int h) {
#pragma unroll
    for (int u = 0; u < 2; ++u) {
        int c = t + (h * 2 + u) * 512;
        int r = c >> 3;
        int kq = (c & 7) ^ (r & 7);  // inverse-swizzled global chunk
        async_cp16(g + (size_t)(row0 + r) * LD + k0 + (kq << 3), lds + c * 8);
    }
}

// Stage B half h (64 rows, 512 chunks, 1 per thread).
template <int LD>
__device__ __forceinline__ void at_stageB_half(const unsigned short* __restrict__ g,
                                               int row0, int k0, unsigned short* lds,
                                               int t, int h) {
    int c = t + h * 512;
    int r = c >> 3;
    int kq = (c & 7) ^ (r & 7);
    async_cp16(g + (size_t)(row0 + r) * LD + k0 + (kq << 3), lds + c * 8);
}

// Full-tile stagers (prologue only).
template <int LD>
__device__ __forceinline__ void at_stageA(const unsigned short* __restrict__ g,
                                          int row0, int k0, unsigned short* lds, int t) {
    at_stageA_half<LD>(g, row0, k0, lds, t, 0);
    at_stageA_half<LD>(g, row0, k0, lds, t, 1);
}
template <int LD>
__device__ __forceinline__ void at_stageB(const unsigned short* __restrict__ g,
                                          int row0, int k0, unsigned short* lds, int t) {
    at_stageB_half<LD>(g, row0, k0, lds, t, 0);
    at_stageB_half<LD>(g, row0, k0, lds, t, 1);
}

// One sub-phase: 8 swizzled ds_read_b128 (K-slice ks of slot cp) + optional
// stage-half ks of a later tile into nsl + 16 MFMA under setprio(1).
// 16-MFMA grain = the m196/m201-proven interleave unit; compiler inserts
// fine lgkmcnt for the read->MFMA deps (rule-18 safe).
template <int LD, int DO_STAGE>
__device__ __forceinline__ void at_sub(const unsigned short* cp,
                                       const unsigned short* __restrict__ A,
                                       const unsigned short* __restrict__ Bt,
                                       int m0, int n0, int kst, unsigned short* nsl,
                                       int t, f32x4 acc[4][4],
                                       int wrow, int wcol, int lane16, int quad, int ks) {
    const unsigned short* As = cp;
    const unsigned short* Bs = cp + 16384;
    bf16x8 a[4], b[4];
    int sw = (((ks << 2) | quad) ^ (lane16 & 7)) << 3;  // row&7 == lane16&7
#pragma unroll
    for (int i = 0; i < 4; ++i)
        a[i] = *(const bf16x8*)&As[(wrow + i * 16 + lane16) * 64 + sw];
#pragma unroll
    for (int j = 0; j < 4; ++j)
        b[j] = *(const bf16x8*)&Bs[(wcol + j * 16 + lane16) * 64 + sw];
    if (DO_STAGE) {
        at_stageA_half<LD>(A, m0, kst, nsl, t, ks);
        at_stageB_half<LD>(Bt, n0, kst, nsl + 16384, t, ks);
    }
    __builtin_amdgcn_s_setprio(1);
#pragma unroll
    for (int i = 0; i < 4; ++i)
#pragma unroll
        for (int j = 0; j < 4; ++j)
            acc[i][j] = __builtin_amdgcn_mfma_f32_16x16x32_bf16(a[i], b[j], acc[i][j], 0, 0, 0);
    __builtin_amdgcn_s_setprio(0);
}

// ---- unified pre-pass ------------------------------------------------------
// z=0: image 64x64 tile -> image_bf + imgT      z=1: text -> text_bf + textT
// z=2: weights flat cvt (lin id over 1024 blocks); blocks 0-3 zero lT/lI.
__global__ void __launch_bounds__(256)
cvt_all(const float* __restrict__ im, const float* __restrict__ tx,
        const float* __restrict__ wt, const float* __restrict__ wi,
        unsigned short* __restrict__ imb, unsigned short* __restrict__ txb,
        unsigned short* __restrict__ imgT, unsigned short* __restrict__ textT,
        unsigned short* __restrict__ wtb, unsigned short* __restrict__ wib,
        float* __restrict__ lTI) {
    int t = threadIdx.x;
    if (blockIdx.z == 2) {
        int lin = blockIdx.y * 64 + blockIdx.x;  // 0..1023
        if (lin < 4) {
            *(f32x4*)&lTI[(lin * 256 + t) * 8] = (f32x4){0.f, 0.f, 0.f, 0.f};
            *(f32x4*)&lTI[(lin * 256 + t) * 8 + 4] = (f32x4){0.f, 0.f, 0.f, 0.f};
        }
        size_t i = (size_t)(lin * 256 + t) * 8;
        const float* s;
        unsigned short* d;
        size_t off;
        if (i < 1048576) { s = wt; d = wtb; off = i; }
        else             { s = wi; d = wib; off = i - 1048576; }
        float4 f0 = *(const float4*)(s + off);
        float4 f1 = *(const float4*)(s + off + 4);
        uint4 o;
        o.x = (unsigned int)f2bf(f0.x) | ((unsigned int)f2bf(f0.y) << 16);
        o.y = (unsigned int)f2bf(f0.z) | ((unsigned int)f2bf(f0.w) << 16);
        o.z = (unsigned int)f2bf(f1.x) | ((unsigned int)f2bf(f1.y) << 16);
        o.w = (unsigned int)f2bf(f1.z) | ((unsigned int)f2bf(f1.w) << 16);
        *(uint4*)(d + off) = o;
        return;
    }
    const float* in = blockIdx.z ? tx : im;
    unsigned short* nb = blockIdx.z ? txb : imb;
    unsigned short* tr = blockIdx.z ? textT : imgT;
    __shared__ float tile[64][65];
    int row0 = blockIdx.x * 64, col0 = blockIdx.y * 64;
    int r = t >> 2, c = (t & 3) << 4;  // 64 rows x 4 col-chunks of 16
    {
        const float* p = in + (size_t)(row0 + r) * DIM + col0 + c;
        float4 f0 = *(const float4*)(p);
        float4 f1 = *(const float4*)(p + 4);
        float4 f2 = *(const float4*)(p + 8);
        float4 f3 = *(const float4*)(p + 12);
        *(float4*)&tile[r][c] = f0;
        *(float4*)&tile[r][c + 4] = f1;
        *(float4*)&tile[r][c + 8] = f2;
        *(float4*)&tile[r][c + 12] = f3;
        uint4 o0, o1;
        o0.x = (unsigned int)f2bf(f0.x) | ((unsigned int)f2bf(f0.y) << 16);
        o0.y = (unsigned int)f2bf(f0.z) | ((unsigned int)f2bf(f0.w) << 16);
        o0.z = (unsigned int)f2bf(f1.x) | ((unsigned int)f2bf(f1.y) << 16);
        o0.w = (unsigned int)f2bf(f1.z) | ((unsigned int)f2bf(f1.w) << 16);
        o1.x = (unsigned int)f2bf(f2.x) | ((unsigned int)f2bf(f2.y) << 16);
        o1.y = (unsigned int)f2bf(f2.z) | ((unsigned int)f2bf(f2.w) << 16);
        o1.z = (unsigned int)f2bf(f3.x) | ((unsigned int)f2bf(f3.y) << 16);
        o1.w = (unsigned int)f2bf(f3.z) | ((unsigned int)f2bf(f3.w) << 16);
        unsigned short* q = nb + (size_t)(row0 + r) * DIM + col0 + c;
        *(uint4*)q = o0;
        *(uint4*)(q + 8) = o1;
    }
    __syncthreads();
    {
        unsigned short v[16];
#pragma unroll
        for (int u = 0; u < 16; ++u) v[u] = f2bf(tile[c + u][r]);
        unsigned short* q = tr + (size_t)(col0 + r) * N_T + row0 + c;
        *(uint4*)q = *(uint4*)&v[0];
        *(uint4*)(q + 8) = *(uint4*)&v[8];
    }
}

// ---- proj v3: fine-phase pipeline, 256x128 tiles, bias epilogue ------------
// C_bf16[4096][1024] = A_bf16 @ W_bf16^T + bias.  grid (16, 8, 2), 512 thr,
// 144 KB dynamic LDS -> 1 blk/CU. K=1024 -> 16 tiles: 14 staged + 2 peeled.
__global__ void __launch_bounds__(512)
gemm_proj3(const unsigned short* __restrict__ Atx, const unsigned short* __restrict__ Wtx,
           const float* __restrict__ btx, unsigned short* __restrict__ Ctx,
           const unsigned short* __restrict__ Aim, const unsigned short* __restrict__ Wim,
           const float* __restrict__ bim, unsigned short* __restrict__ Cim) {
    extern __shared__ unsigned short sm[];  // 3 * AT_SLOT shorts = 144 KB
    int z = blockIdx.z;
    const unsigned short* A = z ? Aim : Atx;
    const unsigned short* W = z ? Wim : Wtx;
    const float* bias = z ? bim : btx;
    unsigned short* C = z ? Cim : Ctx;

    int tid = threadIdx.x;
    int m0 = blockIdx.x * 256, n0 = blockIdx.y * 128;
    int lane = tid & 63, wave = tid >> 6;
    int lane16 = lane & 15, quad = lane >> 4;
    int wrow = (wave >> 1) * 64, wcol = (wave & 1) * 64;  // 4M x 2N waves
    f32x4 acc[4][4];
    {
        f32x4 zz = {0.f, 0.f, 0.f, 0.f};
        for (int i = 0; i < 4; ++i)
            for (int j = 0; j < 4; ++j) acc[i][j] = zz;
    }

    // prologue: slots 0,1 <- tiles 0,1; vmcnt(6) leaves tile 1's 6 newest.
    at_stageA<DIM>(A, m0, 0, sm, tid);
    at_stageB<DIM>(W, n0, 0, sm + 16384, tid);
    at_stageA<DIM>(A, m0, 64, sm + AT_SLOT, tid);
    at_stageB<DIM>(W, n0, 64, sm + AT_SLOT + 16384, tid);
    asm volatile("s_waitcnt vmcnt(6)" ::: "memory");
    __builtin_amdgcn_s_barrier();

    int cur = 0;
    for (int s = 0; s < 14; ++s) {  // DIM/64 - 2 pipelined tiles
        int ns = cur + 2; if (ns >= 3) ns -= 3;
        unsigned short* nsl = sm + ns * AT_SLOT;
        const unsigned short* cp = sm + cur * AT_SLOT;
        int kst = (s + 2) * 64;
        at_sub<DIM, 1>(cp, A, W, m0, n0, kst, nsl, tid, acc, wrow, wcol, lane16, quad, 0);
        asm volatile("" ::: "memory");
        __builtin_amdgcn_s_barrier();
        asm volatile("" ::: "memory");
        at_sub<DIM, 1>(cp, A, W, m0, n0, kst, nsl, tid, acc, wrow, wcol, lane16, quad, 1);
        asm volatile("s_waitcnt vmcnt(6) lgkmcnt(0)" ::: "memory");
        __builtin_amdgcn_s_barrier();
        cur += 1; if (cur >= 3) cur -= 3;
    }
    // tile 14 (no stage); end gate vmcnt(0): tile 15 fully landed.
    {
        const unsigned short* cp = sm + cur * AT_SLOT;
        at_sub<DIM, 0>(cp, A, W, m0, n0, 0, nullptr, tid, acc, wrow, wcol, lane16, quad, 0);
        asm volatile("" ::: "memory");
        __builtin_amdgcn_s_barrier();
        asm volatile("" ::: "memory");
        at_sub<DIM, 0>(cp, A, W, m0, n0, 0, nullptr, tid, acc, wrow, wcol, lane16, quad, 1);
        asm volatile("s_waitcnt vmcnt(0) lgkmcnt(0)" ::: "memory");
        __builtin_amdgcn_s_barrier();
        cur += 1; if (cur >= 3) cur -= 3;
    }
    // tile 15: compute only.
    {
        const unsigned short* cp = sm + cur * AT_SLOT;
        at_sub<DIM, 0>(cp, A, W, m0, n0, 0, nullptr, tid, acc, wrow, wcol, lane16, quad, 0);
        at_sub<DIM, 0>(cp, A, W, m0, n0, 0, nullptr, tid, acc, wrow, wcol, lane16, quad, 1);
    }

#pragma unroll
    for (int j = 0; j < 4; ++j) {
        int col = n0 + wcol + j * 16 + lane16;
        float bv = bias[col];
#pragma unroll
        for (int i = 0; i < 4; ++i) {
            int rowb = m0 + wrow + i * 16 + quad * 4;
#pragma unroll
            for (int r = 0; r < 4; ++r)
                C[(size_t)(rowb + r) * DIM + col] = f2bf(acc[i][j][r] + bv);
        }
    }
}

// ---- logits+exp (r2-exact): P/PT bf16 + fused row/col exp-sums -------------
// 128x128, 256 thr, 4 blk/CU. Wave-pair LDS pre-combine -> one atomic per
// row/col per block. Serial-chain floor ~68 µs (see header ledger).
__global__ void __launch_bounds__(256, 4)
gemm_logits_exp(const unsigned short* __restrict__ Tb,
                const unsigned short* __restrict__ Ib,
                unsigned short* __restrict__ P, unsigned short* __restrict__ PT,
                float* __restrict__ lT, float* __restrict__ lI) {
    __shared__ unsigned short smem[128 * TSS];  // 34.8 KB: K-bufs + epilogue
    unsigned short* As0 = smem;
    unsigned short* Bs0 = smem + 4096;
    unsigned short* As1 = smem + 8192;
    unsigned short* Bs1 = smem + 12288;
    float* lred = (float*)(smem + 16384);  // 128 floats (free tail of smem)
    float* cred = lred + 128;              // 128 floats
    int tid = threadIdx.x;
    int m0 = blockIdx.x * 128, n0 = blockIdx.y * 128;
    int lane = tid & 63, wave = tid >> 6;
    int lane16 = lane & 15, quad = lane >> 4;
    int wrow = (wave >> 1) * 64, wcol = (wave & 1) * 64;
    f32x4 acc[4][4];
    {
        f32x4 z = {0.f, 0.f, 0.f, 0.f};
        for (int i = 0; i < 4; ++i)
            for (int j = 0; j < 4; ++j) acc[i][j] = z;
    }
    for (int k0 = 0; k0 < DIM; k0 += 64) {
        stage_async(Tb, DIM, m0, k0, As0, tid);
        stage_async(Ib, DIM, n0, k0, Bs0, tid);
        stage_async(Tb, DIM, m0, k0 + 32, As1, tid);
        stage_async(Ib, DIM, n0, k0 + 32, Bs1, tid);
        __syncthreads();
        mfma_step(As0, Bs0, acc, wrow, wcol, lane16, quad);
        mfma_step(As1, Bs1, acc, wrow, wcol, lane16, quad);
        __syncthreads();
    }
    // p = exp(logit/32) in place (fp32)
#pragma unroll
    for (int i = 0; i < 4; ++i)
#pragma unroll
        for (int j = 0; j < 4; ++j)
#pragma unroll
            for (int r = 0; r < 4; ++r)
                acc[i][j][r] = __expf(acc[i][j][r] * 0.03125f);
    // wave partials: rows (this wave's 64 cols) and cols (this wave's 64 rows)
    float rs[4][4];  // row partial, valid at lane16==0
#pragma unroll
    for (int i = 0; i < 4; ++i)
#pragma unroll
        for (int r = 0; r < 4; ++r) {
            float s = acc[i][0][r] + acc[i][1][r] + acc[i][2][r] + acc[i][3][r];
            s += __shfl_xor(s, 1); s += __shfl_xor(s, 2);
            s += __shfl_xor(s, 4); s += __shfl_xor(s, 8);
            rs[i][r] = s;
        }
    float cs[4];  // col partial, valid at quad==0
#pragma unroll
    for (int j = 0; j < 4; ++j) {
        float s = 0.f;
#pragma unroll
        for (int i = 0; i < 4; ++i)
#pragma unroll
            for (int r = 0; r < 4; ++r) s += acc[i][j][r];
        s += __shfl_xor(s, 16); s += __shfl_xor(s, 32);
        cs[j] = s;
    }
    // donors: waves 1,3 stash row partials; waves 2,3 stash col partials
    if (wave & 1) {
        if (lane16 == 0)
#pragma unroll
            for (int i = 0; i < 4; ++i)
#pragma unroll
                for (int r = 0; r < 4; ++r)
                    lred[wrow + i * 16 + quad * 4 + r] = rs[i][r];
    }
    if (wave >> 1) {
        if (quad == 0)
#pragma unroll
            for (int j = 0; j < 4; ++j)
                cred[wcol + j * 16 + lane16] = cs[j];
    }
    __syncthreads();
    // combiners: waves 0,2 finish rows; waves 0,1 finish cols
    if (!(wave & 1) && lane16 == 0) {
#pragma unroll
        for (int i = 0; i < 4; ++i)
#pragma unroll
            for (int r = 0; r < 4; ++r) {
                int row = wrow + i * 16 + quad * 4 + r;
                atomicAdd(&lT[m0 + row], rs[i][r] + lred[row]);
            }
    }
    if (!(wave >> 1) && quad == 0) {
#pragma unroll
        for (int j = 0; j < 4; ++j) {
            int col = wcol + j * 16 + lane16;
            atomicAdd(&lI[n0 + col], cs[j] + cred[col]);
        }
    }
    // pass 1: normal-layout tile -> P (coalesced b128 stores)
    __syncthreads();
#pragma unroll
    for (int i = 0; i < 4; ++i)
#pragma unroll
        for (int j = 0; j < 4; ++j)
#pragma unroll
            for (int r = 0; r < 4; ++r)
                smem[(wrow + i * 16 + quad * 4 + r) * TSS + wcol + j * 16 + lane16] =
                    f2bf(acc[i][j][r]);
    __syncthreads();
    tile_store(smem, P, N_I, m0, n0, tid);
    // pass 2: transposed tile -> PT (b64 LDS writes, coalesced b128 stores)
    __syncthreads();
#pragma unroll
    for (int i = 0; i < 4; ++i)
#pragma unroll
        for (int j = 0; j < 4; ++j) {
            unsigned int lo = (unsigned int)f2bf(acc[i][j][0]) |
                              ((unsigned int)f2bf(acc[i][j][1]) << 16);
            unsigned int hi = (unsigned int)f2bf(acc[i][j][2]) |
                              ((unsigned int)f2bf(acc[i][j][3]) << 16);
            uint2 v; v.x = lo; v.y = hi;
            *(uint2*)&smem[(wcol + j * 16 + lane16) * TSS + wrow + i * 16 + quad * 4] = v;
        }
    __syncthreads();
    tile_store(smem, PT, N_T, n0, m0, tid);
}

// ---- attn v3 (r2-verified): fine-phase pipeline ----------------------------
// grid (16, 8, 2), 512 thr, 144 KB dynamic LDS -> 1 block/CU, 8 waves.
// Tile protocol: {sub0; barrier; sub1; vmcnt(6)+lgkmcnt(0); barrier}.
__global__ void __launch_bounds__(512)
gemm_attn3(const unsigned short* __restrict__ P, const unsigned short* __restrict__ imgT,
           const float* __restrict__ lT, const float* __restrict__ sTI,
           float* __restrict__ out0,
           const unsigned short* __restrict__ PT, const unsigned short* __restrict__ textT,
           const float* __restrict__ lI, const float* __restrict__ sIT,
           float* __restrict__ out1) {
    extern __shared__ unsigned short sm[];  // 3 * AT_SLOT shorts = 144 KB
    int which = blockIdx.z;
    const unsigned short* A = which ? PT : P;
    const unsigned short* Bt = which ? textT : imgT;
    const float* l = which ? lI : lT;
    const float* sp = which ? sIT : sTI;
    float* out = which ? out1 : out0;

    int tid = threadIdx.x;
    int m0 = blockIdx.x * 256, n0 = blockIdx.y * 128;
    int lane = tid & 63, wave = tid >> 6;
    int lane16 = lane & 15, quad = lane >> 4;
    int wrow = (wave >> 1) * 64, wcol = (wave & 1) * 64;  // 4M x 2N waves
    f32x4 acc[4][4];
    {
        f32x4 z = {0.f, 0.f, 0.f, 0.f};
        for (int i = 0; i < 4; ++i)
            for (int j = 0; j < 4; ++j) acc[i][j] = z;
    }

    // prologue: slots 0,1 <- tiles 0,1; vmcnt(6) leaves tile 1's 6 newest.
    at_stageA<4096>(A, m0, 0, sm, tid);
    at_stageB<4096>(Bt, n0, 0, sm + 16384, tid);
    at_stageA<4096>(A, m0, 64, sm + AT_SLOT, tid);
    at_stageB<4096>(Bt, n0, 64, sm + AT_SLOT + 16384, tid);
    asm volatile("s_waitcnt vmcnt(6)" ::: "memory");
    __builtin_amdgcn_s_barrier();

    int cur = 0;
    for (int s = 0; s < 62; ++s) {
        int ns = cur + 2; if (ns >= 3) ns -= 3;
        unsigned short* nsl = sm + ns * AT_SLOT;
        const unsigned short* cp = sm + cur * AT_SLOT;
        int kst = (s + 2) * 64;
        at_sub<4096, 1>(cp, A, Bt, m0, n0, kst, nsl, tid, acc, wrow, wcol, lane16, quad, 0);
        asm volatile("" ::: "memory");
        __builtin_amdgcn_s_barrier();
        asm volatile("" ::: "memory");
        at_sub<4096, 1>(cp, A, Bt, m0, n0, kst, nsl, tid, acc, wrow, wcol, lane16, quad, 1);
        asm volatile("s_waitcnt vmcnt(6) lgkmcnt(0)" ::: "memory");
        __builtin_amdgcn_s_barrier();
        cur += 1; if (cur >= 3) cur -= 3;
    }
    // tile 62 (no stage); end gate vmcnt(0): tile 63 fully landed.
    {
        const unsigned short* cp = sm + cur * AT_SLOT;
        at_sub<4096, 0>(cp, A, Bt, m0, n0, 0, nullptr, tid, acc, wrow, wcol, lane16, quad, 0);
        asm volatile("" ::: "memory");
        __builtin_amdgcn_s_barrier();
        asm volatile("" ::: "memory");
        at_sub<4096, 0>(cp, A, Bt, m0, n0, 0, nullptr, tid, acc, wrow, wcol, lane16, quad, 1);
        asm volatile("s_waitcnt vmcnt(0) lgkmcnt(0)" ::: "memory");
        __builtin_amdgcn_s_barrier();
        cur += 1; if (cur >= 3) cur -= 3;
    }
    // tile 63: compute only.
    {
        const unsigned short* cp = sm + cur * AT_SLOT;
        at_sub<4096, 0>(cp, A, Bt, m0, n0, 0, nullptr, tid, acc, wrow, wcol, lane16, quad, 0);
        at_sub<4096, 0>(cp, A, Bt, m0, n0, 0, nullptr, tid, acc, wrow, wcol, lane16, quad, 1);
    }

    float sc = sp[0];
#pragma unroll
    for (int i = 0; i < 4; ++i) {
        int rowb = m0 + wrow + i * 16 + quad * 4;
        float fac[4];
#pragma unroll
        for (int r = 0; r < 4; ++r) fac[r] = sc / l[rowb + r];
#pragma unroll
        for (int j = 0; j < 4; ++j) {
            int col = n0 + wcol + j * 16 + lane16;
#pragma unroll
            for (int r = 0; r < 4; ++r)
                out[(size_t)(rowb + r) * DIM + col] = acc[i][j][r] * fac[r];
        }
    }
}

extern "C" void kernel_launch(void* const* d_in, const int* in_sizes, int n_in,
                              void* d_out, int out_size, void* d_ws, size_t ws_size,
                              hipStream_t stream) {
    const float* text = (const float*)d_in[0];
    const float* image = (const float*)d_in[1];
    const float* w_text = (const float*)d_in[2];
    const float* b_text = (const float*)d_in[3];
    const float* w_image = (const float*)d_in[4];
    const float* b_image = (const float*)d_in[5];
    const float* scale_TI = (const float*)d_in[6];
    const float* scale_IT = (const float*)d_in[7];
    float* out0 = (float*)d_out;
    float* out1 = out0 + (size_t)N_T * DIM;

    // Workspace layout (96 MB + 32 KB). cvt buffers [0,20MB) die after proj;
    // gemm_logits_exp then writes P over [0,32MB) — lifetimes disjoint.
    char* ws = (char*)d_ws;
    unsigned short* text_bf = (unsigned short*)(ws);                 // 8 MB  (dies after proj)
    unsigned short* image_bf = (unsigned short*)(ws + (8ull << 20)); // 8 MB  (dies after proj)
    unsigned short* wt_bf = (unsigned short*)(ws + (16ull << 20));   // 2 MB  (dies after proj)
    unsigned short* wi_bf = (unsigned short*)(ws + (18ull << 20));   // 2 MB  (dies after proj)
    unsigned short* P = (unsigned short*)(ws);                       // 32 MB (logits -> attn)
    unsigned short* imgT = (unsigned short*)(ws + (32ull << 20));    // 8 MB
    unsigned short* textT = (unsigned short*)(ws + (40ull << 20));   // 8 MB
    unsigned short* t_bf = (unsigned short*)(ws + (48ull << 20));    // 8 MB
    unsigned short* i_bf = (unsigned short*)(ws + (56ull << 20));    // 8 MB
    unsigned short* PT = (unsigned short*)(ws + (64ull << 20));      // 32 MB
    float* lT = (float*)(ws + (96ull << 20));                        // 16 KB
    float* lI = (float*)(ws + (96ull << 20) + 16384);                // 16 KB

    // 144 KB dynamic LDS (one-time host attribute; safe under graph capture).
    static bool lds_set = false;
    if (!lds_set) {
        hipFuncSetAttribute((const void*)gemm_attn3,
                            hipFuncAttributeMaxDynamicSharedMemorySize, AT_LDS_BYTES);
        hipFuncSetAttribute((const void*)gemm_proj3,
                            hipFuncAttributeMaxDynamicSharedMemorySize, AT_LDS_BYTES);
        lds_set = true;
    }

    // z=0/1: feature 64x64 cvt+transpose tiles; z=2: weights cvt + lT/lI zero.
    cvt_all<<<dim3(N_T / 64, DIM / 64, 3), 256, 0, stream>>>(
        image, text, w_text, w_image, image_bf, text_bf, imgT, textT,
        wt_bf, wi_bf, lT);

    gemm_proj3<<<dim3(N_T / 256, DIM / 128, 2), 512, AT_LDS_BYTES, stream>>>(
        text_bf, wt_bf, b_text, t_bf, image_bf, wi_bf, b_image, i_bf);

    gemm_logits_exp<<<dim3(N_T / 128, N_I / 128), 256, 0, stream>>>(t_bf, i_bf, P, PT, lT, lI);

    gemm_attn3<<<dim3(N_T / 256, DIM / 128, 2), 512, AT_LDS_BYTES, stream>>>(
        P, imgT, lT, scale_TI, out0, PT, textT, lI, scale_IT, out1);
}